// Round 1
// baseline (589.124 us; speedup 1.0000x reference)
//
#include <hip/hip_runtime.h>
#include <stdint.h>

// Superpoint pooling via 29-bit key bitmap + prefix-popcount ranking.
// key = batch(2b) | qx(9b) | qy(9b) | qz(9b); numeric order == lexicographic order,
// so exclusive prefix popcount over the presence bitmap == jnp.unique sorted rank.

static constexpr uint32_t NWORDS = 1u << 24;   // 2^29 bits / 32

__device__ __forceinline__ uint32_t point_key(float4 c) {
    uint32_t b  = (uint32_t)(int)c.x;
    uint32_t qx = (uint32_t)(int)floorf(c.y / 0.1f);
    uint32_t qy = (uint32_t)(int)floorf(c.z / 0.1f);
    uint32_t qz = (uint32_t)(int)floorf(c.w / 0.1f);
    return (b << 27) | (qx << 18) | (qy << 9) | qz;
}

__global__ void k1_keys(const float4* __restrict__ coords, uint32_t* __restrict__ keys,
                        uint32_t* __restrict__ bitmap, int N) {
    int i = blockIdx.x * blockDim.x + threadIdx.x;
    if (i >= N) return;
    uint32_t key = point_key(coords[i]);
    keys[i] = key;
    atomicOr(&bitmap[key >> 5], 1u << (key & 31u));
}

// Per-256-word block: popcount scan. Writes per-8-word within-block exclusive
// prefix (uint16, max 255*32=8160 fits) and per-block total.
__global__ void k2a_blockscan(const uint32_t* __restrict__ bitmap,
                              uint16_t* __restrict__ scan8,
                              uint32_t* __restrict__ bsum) {
    __shared__ uint32_t s[256];
    int t = threadIdx.x;
    uint32_t w = blockIdx.x * 256u + t;
    uint32_t pc = __popc(bitmap[w]);
    s[t] = pc;
    __syncthreads();
    for (int off = 1; off < 256; off <<= 1) {
        uint32_t v = (t >= off) ? s[t - off] : 0u;
        __syncthreads();
        s[t] += v;
        __syncthreads();
    }
    if ((t & 7) == 0) scan8[w >> 3] = (uint16_t)(s[t] - pc);   // exclusive at group start
    if (t == 255) bsum[blockIdx.x] = s[255];
}

// Exclusive scan of 65536 block sums; bscan[65536] = total unique count U.
__global__ void k2b_topscan(const uint32_t* __restrict__ bsum, uint32_t* __restrict__ bscan) {
    __shared__ uint32_t s[1024];
    int t = threadIdx.x;
    uint32_t base = (uint32_t)t * 64u;
    uint32_t sum = 0;
    for (int k = 0; k < 64; ++k) sum += bsum[base + k];
    s[t] = sum;
    __syncthreads();
    for (int off = 1; off < 1024; off <<= 1) {
        uint32_t v = (t >= off) ? s[t - off] : 0u;
        __syncthreads();
        s[t] += v;
        __syncthreads();
    }
    uint32_t run = s[t] - sum;
    for (int k = 0; k < 64; ++k) { bscan[base + k] = run; run += bsum[base + k]; }
    if (t == 1023) bscan[65536] = run;
}

__global__ void k3_rank(const float4* __restrict__ coords,
                        uint32_t* __restrict__ keys,   // in: keys, out: ranks
                        const uint32_t* __restrict__ bitmap,
                        const uint16_t* __restrict__ scan8,
                        const uint32_t* __restrict__ bscan,
                        uint32_t* __restrict__ count,
                        float* __restrict__ xyzsum,
                        float* __restrict__ out_sp, int N) {
    int i = blockIdx.x * blockDim.x + threadIdx.x;
    if (i >= N) return;
    uint32_t key = keys[i];
    uint32_t w = key >> 5, bit = key & 31u;
    uint32_t r = bscan[w >> 8] + (uint32_t)scan8[w >> 3];
    for (uint32_t x = (w & ~7u); x < w; ++x) r += __popc(bitmap[x]);
    r += __popc(bitmap[w] & ((1u << bit) - 1u));
    keys[i] = r;
    out_sp[i] = (float)r;
    atomicAdd(&count[r], 1u);
    float4 c = coords[i];
    atomicAdd(&xyzsum[3u * r + 0], c.y);
    atomicAdd(&xyzsum[3u * r + 1], c.z);
    atomicAdd(&xyzsum[3u * r + 2], c.w);
}

// out[64] += b2 + relu(c@W1+b1) @ W2.  k rolled (hk recomputed, W1/W2 rows are
// wave-uniform scalar loads), j unrolled (static indexing keeps out[] in VGPRs).
__device__ __forceinline__ void mlp_add(float cx, float cy, float cz,
        const float* __restrict__ W1, const float* __restrict__ b1,
        const float* __restrict__ W2, const float* __restrict__ b2,
        float out[64]) {
    #pragma unroll
    for (int j = 0; j < 64; ++j) out[j] += b2[j];
    #pragma unroll 1
    for (int k = 0; k < 64; ++k) {
        float hk = fmaxf(b1[k] + cx * W1[k] + cy * W1[64 + k] + cz * W1[128 + k], 0.0f);
        #pragma unroll
        for (int j = 0; j < 64; ++j) out[j] = fmaf(hk, W2[64 * k + j], out[j]);
    }
}

__global__ __launch_bounds__(256) void k4_centers(
        const uint32_t* __restrict__ count, const float* __restrict__ xyzsum,
        const float* __restrict__ W1, const float* __restrict__ b1,
        const float* __restrict__ W2, const float* __restrict__ b2,
        float* __restrict__ out_feat, float* __restrict__ out_cent, int N) {
    int r = blockIdx.x * blockDim.x + threadIdx.x;
    if (r >= N) return;
    uint32_t c = count[r];
    if (c == 0) {
        float4 z = make_float4(0.f, 0.f, 0.f, 0.f);
        float4* fr = (float4*)(out_feat + (size_t)r * 64);
        #pragma unroll
        for (int q = 0; q < 16; ++q) fr[q] = z;
        out_cent[3 * (size_t)r + 0] = 0.f;
        out_cent[3 * (size_t)r + 1] = 0.f;
        out_cent[3 * (size_t)r + 2] = 0.f;
        return;
    }
    float inv = 1.0f / (float)c;
    float cx = xyzsum[3u * r + 0] * inv;
    float cy = xyzsum[3u * r + 1] * inv;
    float cz = xyzsum[3u * r + 2] * inv;
    out_cent[3 * (size_t)r + 0] = cx;
    out_cent[3 * (size_t)r + 1] = cy;
    out_cent[3 * (size_t)r + 2] = cz;
    if (c > 1) {   // rare (~0.1%): write pos; k5 atomic-adds f/c on top
        float out[64];
        #pragma unroll
        for (int j = 0; j < 64; ++j) out[j] = 0.f;
        mlp_add(cx, cy, cz, W1, b1, W2, b2, out);
        float* fr = out_feat + (size_t)r * 64;
        #pragma unroll
        for (int j = 0; j < 64; ++j) fr[j] = out[j];
    }
}

__global__ __launch_bounds__(256) void k5_features(
        const float4* __restrict__ coords, const float* __restrict__ features,
        const uint32_t* __restrict__ ranks, const uint32_t* __restrict__ count,
        const float* __restrict__ W1, const float* __restrict__ b1,
        const float* __restrict__ W2, const float* __restrict__ b2,
        float* __restrict__ out_feat, int N) {
    int i = blockIdx.x * blockDim.x + threadIdx.x;
    if (i >= N) return;
    uint32_t r = ranks[i];
    uint32_t c = count[r];
    const float* frow = features + (size_t)i * 64;
    if (c == 1) {   // singleton: center == own xyz; single clean row write
        float4 cc = coords[i];
        float out[64];
        const float4* f4 = (const float4*)frow;
        #pragma unroll
        for (int q = 0; q < 16; ++q) {
            float4 f = f4[q];
            out[4*q+0] = f.x; out[4*q+1] = f.y; out[4*q+2] = f.z; out[4*q+3] = f.w;
        }
        mlp_add(cc.y, cc.z, cc.w, W1, b1, W2, b2, out);
        float4* orow = (float4*)(out_feat + (size_t)r * 64);
        #pragma unroll
        for (int q = 0; q < 16; ++q)
            orow[q] = make_float4(out[4*q], out[4*q+1], out[4*q+2], out[4*q+3]);
    } else {
        float inv = 1.0f / (float)c;
        float* orow = out_feat + (size_t)r * 64;
        #pragma unroll 1
        for (int q = 0; q < 64; ++q) atomicAdd(&orow[q], frow[q] * inv);
    }
}

__global__ void k6_offsets(const uint32_t* __restrict__ bscan, float* __restrict__ out_off) {
    int t = threadIdx.x;
    if (t < 5) {
        uint32_t v;
        if (t == 0)      v = 0u;
        else if (t == 4) v = bscan[65536];
        else             v = bscan[(uint32_t)t << 14];   // rank at key b<<27
        out_off[t] = (float)v;
    }
}

extern "C" void kernel_launch(void* const* d_in, const int* in_sizes, int n_in,
                              void* d_out, int out_size, void* d_ws, size_t ws_size,
                              hipStream_t stream) {
    const float4* coords = (const float4*)d_in[0];
    const float*  feats  = (const float*)d_in[1];
    const float*  W1 = (const float*)d_in[2];
    const float*  b1 = (const float*)d_in[3];
    const float*  W2 = (const float*)d_in[4];
    const float*  b2 = (const float*)d_in[5];
    int N = in_sizes[0] / 4;

    char* ws = (char*)d_ws;
    uint32_t* bitmap = (uint32_t*)ws;                                  // 64 MB
    uint16_t* scan8  = (uint16_t*)(ws + (1u << 26));                   // 4 MB
    uint32_t* bsum   = (uint32_t*)(ws + (1u << 26) + (1u << 22));      // 256 KB
    uint32_t* bscan  = bsum + 65536;                                   // 65537 u32
    uint32_t* keys   = bscan + 65537;                                  // 4N B (keys->ranks)
    uint32_t* count  = keys + N;                                       // 4N B
    float*    xyzsum = (float*)(count + N);                            // 12N B

    float* out_feat = (float*)d_out;
    float* out_cent = out_feat + (size_t)N * 64;
    float* out_sp   = out_cent + (size_t)N * 3;
    float* out_off  = out_sp + N;

    hipMemsetAsync(bitmap, 0, (size_t)NWORDS * 4u, stream);
    hipMemsetAsync(count, 0, (size_t)N * 16u, stream);   // count + xyzsum contiguous

    int nb = (N + 255) / 256;
    k1_keys<<<nb, 256, 0, stream>>>(coords, keys, bitmap, N);
    k2a_blockscan<<<NWORDS / 256, 256, 0, stream>>>(bitmap, scan8, bsum);
    k2b_topscan<<<1, 1024, 0, stream>>>(bsum, bscan);
    k3_rank<<<nb, 256, 0, stream>>>(coords, keys, bitmap, scan8, bscan, count, xyzsum, out_sp, N);
    k4_centers<<<nb, 256, 0, stream>>>(count, xyzsum, W1, b1, W2, b2, out_feat, out_cent, N);
    k5_features<<<nb, 256, 0, stream>>>(coords, feats, keys, count, W1, b1, W2, b2, out_feat, N);
    k6_offsets<<<1, 64, 0, stream>>>(bscan, out_off);
}